// Round 1
// baseline (497.985 us; speedup 1.0000x reference)
//
#include <hip/hip_runtime.h>

#define B_   32
#define S_   8192
#define T_   256
#define IN_  4096
#define H_   512
#define OUT_ 10
#define CAP_ 192   // max events per (b,t) bucket; Poisson(32) -> P(>192) ~ 0

// ---------------------------------------------------------------------------
// Tiled transpose: src[R][C] -> dst[C][R]
// ---------------------------------------------------------------------------
__global__ void transpose_k(const float* __restrict__ src, float* __restrict__ dst,
                            int R, int C) {
    __shared__ float tile[32][33];
    int bx = blockIdx.x * 32;  // col base
    int by = blockIdx.y * 32;  // row base
    int tx = threadIdx.x, ty = threadIdx.y;  // 32 x 8
    #pragma unroll
    for (int k = 0; k < 32; k += 8) {
        int r = by + ty + k, c = bx + tx;
        if (r < R && c < C) tile[ty + k][tx] = src[(size_t)r * C + c];
    }
    __syncthreads();
    #pragma unroll
    for (int k = 0; k < 32; k += 8) {
        int c = bx + ty + k, r = by + tx;
        if (c < C && r < R) dst[(size_t)c * R + r] = tile[tx][ty + k];
    }
}

// ---------------------------------------------------------------------------
// Scatter events into (b,t) buckets. key = (pos<<14) | (s<<1) | val
// winner of a (pos) group inside a bucket = max key (i.e. max s), so bucket
// slot order (atomic, nondeterministic) does not affect the result.
// ---------------------------------------------------------------------------
__global__ void scatter_k(const int4* __restrict__ x, int* __restrict__ cnt,
                          unsigned* __restrict__ data) {
    int e = blockIdx.x * blockDim.x + threadIdx.x;
    if (e >= B_ * S_) return;
    int4 ev = x[e];                    // cx, cy, val, ts
    int b = e >> 13;                   // S_ = 8192
    int s = e & (S_ - 1);
    unsigned pos = (unsigned)(ev.x * ev.y);
    unsigned key = (pos << 14) | ((unsigned)s << 1) | (unsigned)ev.z;
    int bucket = b * T_ + ev.w;
    int slot = atomicAdd(&cnt[bucket], 1);
    if (slot < CAP_) data[bucket * CAP_ + slot] = key;
}

// ---------------------------------------------------------------------------
// Per-bucket dedup + input-current accumulation.
// One block per (b,t); block owns in_cur[t, b, :] exclusively (no atomics).
// ---------------------------------------------------------------------------
__global__ __launch_bounds__(512) void incur_k(const int* __restrict__ cnt,
                                               const unsigned* __restrict__ data,
                                               const float* __restrict__ w_in_T,
                                               float* __restrict__ in_cur) {
    int bucket = blockIdx.x;       // b*T_ + t
    int b = bucket >> 8;
    int t = bucket & (T_ - 1);
    __shared__ unsigned keys[CAP_];
    __shared__ unsigned char winflag[CAP_];
    __shared__ unsigned short plist[CAP_];
    __shared__ int mcnt;
    int tid = threadIdx.x;
    int n = cnt[bucket]; if (n > CAP_) n = CAP_;
    if (tid < n) keys[tid] = data[bucket * CAP_ + tid];
    __syncthreads();
    if (tid < n) {
        unsigned ki = keys[tid], pi = ki >> 14;
        bool win = (ki & 1u) != 0u;          // only val==1 winners contribute
        if (win) {
            for (int j = 0; j < n; ++j) {
                unsigned kj = keys[j];
                if ((kj >> 14) == pi && kj > ki) { win = false; break; }
            }
        }
        winflag[tid] = win ? 1 : 0;
    }
    __syncthreads();
    if (tid == 0) {
        int m = 0;
        for (int j = 0; j < n; ++j)
            if (winflag[j]) plist[m++] = (unsigned short)(keys[j] >> 14);
        // insertion sort by pos: deterministic summation order across runs
        for (int a = 1; a < m; ++a) {
            unsigned short xv = plist[a]; int c = a - 1;
            while (c >= 0 && plist[c] > xv) { plist[c + 1] = plist[c]; --c; }
            plist[c + 1] = xv;
        }
        mcnt = m;
    }
    __syncthreads();
    int m = mcnt;
    float acc = 0.f;
    for (int k = 0; k < m; ++k)
        acc += w_in_T[(int)plist[k] * H_ + tid];   // coalesced column gather
    in_cur[(size_t)t * (B_ * H_) + b * H_ + tid] = acc;
}

// ---------------------------------------------------------------------------
// Sequential LIF simulation: one block per batch, thread = hidden unit.
// Spike state shared as 8x u64 bitmasks (double-buffered in LDS).
// ---------------------------------------------------------------------------
__global__ __launch_bounds__(512) void sim_k(const float* __restrict__ in_cur,
                                             const float* __restrict__ w_rec_T,
                                             const float* __restrict__ w_out,
                                             float* __restrict__ out) {
    int b = blockIdx.x;
    int tid = threadIdx.x;
    int wid = tid >> 6, lane = tid & 63;
    __shared__ unsigned long long masks[2][8];
    if (tid < 16) ((unsigned long long*)masks)[tid] = 0ULL;
    __syncthreads();

    float v = 0.f, cur = 0.f;      // membrane / synaptic state of unit h=tid
    float vo = 0.f, io = 0.f;      // LI readout state (lanes 0..9 of wave 0)
    const float* icb = in_cur + b * H_;
    int p = 0;
    for (int t = 0; t < T_; ++t) {
        float inc = icb[(size_t)t * (B_ * H_) + tid];  // issue load early
        // LIF cell (lif_step): v_dec uses old i
        float v_dec = fmaf(0.1f, cur - v, v);          // v + DT*TAU_MEM_INV*(i-v)
        cur *= 0.8f;                                   // i * (1 - DT*TAU_SYN_INV)
        bool z = v_dec > 0.5f;                         // heaviside(v_dec - V_TH)
        v = z ? 0.f : v_dec;
        unsigned long long bal = __ballot(z);
        if (lane == 0) masks[p][wid] = bal;
        __syncthreads();
        // recurrent current from z_prev (masks[p^1]) — sparse gather
        #pragma unroll 1
        for (int w = 0; w < 8; ++w) {
            unsigned long long m = masks[p ^ 1][w];
            while (m) {
                int j = __builtin_ctzll(m);
                cur += w_rec_T[((w << 6) + j) * H_ + tid];
                m &= m - 1;
            }
        }
        cur += inc;
        // readout: y = z_new @ w_out.T, then LI cell; lanes 0..9 own outputs
        if (tid < OUT_) {
            float y = 0.f;
            #pragma unroll 1
            for (int w = 0; w < 8; ++w) {
                unsigned long long m = masks[p][w];
                while (m) {
                    int j = __builtin_ctzll(m);
                    y += w_out[tid * H_ + ((w << 6) + j)];
                    m &= m - 1;
                }
            }
            vo = fmaf(0.1f, io - vo, vo);              // uses OLD io
            io = io * 0.8f + y;
            out[(size_t)t * (B_ * OUT_) + b * OUT_ + tid] = vo;
        }
        __syncthreads();   // protect masks[p^1] before next-iter overwrite
        p ^= 1;
    }
}

// ---------------------------------------------------------------------------
extern "C" void kernel_launch(void* const* d_in, const int* in_sizes, int n_in,
                              void* d_out, int out_size, void* d_ws, size_t ws_size,
                              hipStream_t stream) {
    const int*   x     = (const int*)d_in[0];
    const float* w_in  = (const float*)d_in[1];
    const float* w_rec = (const float*)d_in[2];
    const float* w_out = (const float*)d_in[3];
    float* out = (float*)d_out;

    char* ws = (char*)d_ws;
    size_t off = 0;
    int*      cnt     = (int*)(ws + off);      off += (size_t)B_ * T_ * 4;            // 32 KB
    unsigned* data    = (unsigned*)(ws + off); off += (size_t)B_ * T_ * CAP_ * 4;     // 6 MB
    float*    w_in_T  = (float*)(ws + off);    off += (size_t)IN_ * H_ * 4;           // 8 MB
    float*    w_rec_T = (float*)(ws + off);    off += (size_t)H_ * H_ * 4;            // 1 MB
    float*    in_cur  = (float*)(ws + off);    off += (size_t)T_ * B_ * H_ * 4;       // 16 MB

    hipMemsetAsync(cnt, 0, (size_t)B_ * T_ * 4, stream);

    dim3 tb(32, 8);
    transpose_k<<<dim3(IN_ / 32, H_ / 32), tb, 0, stream>>>(w_in, w_in_T, H_, IN_);
    transpose_k<<<dim3(H_ / 32, H_ / 32), tb, 0, stream>>>(w_rec, w_rec_T, H_, H_);

    scatter_k<<<(B_ * S_) / 256, 256, 0, stream>>>((const int4*)x, cnt, data);

    incur_k<<<B_ * T_, 512, 0, stream>>>(cnt, data, w_in_T, in_cur);

    sim_k<<<B_, 512, 0, stream>>>(in_cur, w_rec_T, w_out, out);
}

// Round 2
// 374.407 us; speedup vs baseline: 1.3301x; 1.3301x over previous
//
#include <hip/hip_runtime.h>

#define B_   32
#define S_   8192
#define T_   256
#define IN_  4096
#define H_   512
#define OUT_ 10
#define CAP_ 192   // max events per (b,t) bucket; Poisson(32) -> P(>192) ~ 0
#define KB   16    // gather batch depth in sim_k

// ---------------------------------------------------------------------------
// Tiled transpose: src[R][C] -> dst[C][R]
// ---------------------------------------------------------------------------
__global__ void transpose_k(const float* __restrict__ src, float* __restrict__ dst,
                            int R, int C) {
    __shared__ float tile[32][33];
    int bx = blockIdx.x * 32;  // col base
    int by = blockIdx.y * 32;  // row base
    int tx = threadIdx.x, ty = threadIdx.y;  // 32 x 8
    #pragma unroll
    for (int k = 0; k < 32; k += 8) {
        int r = by + ty + k, c = bx + tx;
        if (r < R && c < C) tile[ty + k][tx] = src[(size_t)r * C + c];
    }
    __syncthreads();
    #pragma unroll
    for (int k = 0; k < 32; k += 8) {
        int c = bx + ty + k, r = by + tx;
        if (c < C && r < R) dst[(size_t)c * R + r] = tile[tx][ty + k];
    }
}

// ---------------------------------------------------------------------------
// Scatter events into (b,t) buckets. key = (pos<<14) | (s<<1) | val
// winner of a (pos) group inside a bucket = max key (i.e. max s) -> matches
// numpy last-write-wins, independent of atomic slot order.
// ---------------------------------------------------------------------------
__global__ void scatter_k(const int4* __restrict__ x, int* __restrict__ cnt,
                          unsigned* __restrict__ data) {
    int e = blockIdx.x * blockDim.x + threadIdx.x;
    if (e >= B_ * S_) return;
    int4 ev = x[e];                    // cx, cy, val, ts
    int b = e >> 13;                   // S_ = 8192
    int s = e & (S_ - 1);
    unsigned pos = (unsigned)(ev.x * ev.y);
    unsigned key = (pos << 14) | ((unsigned)s << 1) | (unsigned)ev.z;
    int bucket = b * T_ + ev.w;
    int slot = atomicAdd(&cnt[bucket], 1);
    if (slot < CAP_) data[bucket * CAP_ + slot] = key;
}

// ---------------------------------------------------------------------------
// Per-bucket dedup + input-current accumulation.
// One block per (b,t); block owns in_cur[t, b, :] exclusively (no atomics).
// Gather: 8 loads issued per round (latency pipelined), adds kept in the
// exact ascending-pos serial order (bit-exact vs np).
// ---------------------------------------------------------------------------
__global__ __launch_bounds__(512) void incur_k(const int* __restrict__ cnt,
                                               const unsigned* __restrict__ data,
                                               const float* __restrict__ w_in_T,
                                               float* __restrict__ in_cur) {
    int bucket = blockIdx.x;       // b*T_ + t
    int b = bucket >> 8;
    int t = bucket & (T_ - 1);
    __shared__ unsigned keys[CAP_];
    __shared__ unsigned char winflag[CAP_];
    __shared__ unsigned short plist[CAP_ + 8];
    __shared__ int mcnt;
    int tid = threadIdx.x;
    int n = cnt[bucket]; if (n > CAP_) n = CAP_;
    if (tid < n) keys[tid] = data[bucket * CAP_ + tid];
    __syncthreads();
    if (tid < n) {
        unsigned ki = keys[tid], pi = ki >> 14;
        bool win = (ki & 1u) != 0u;          // only val==1 winners contribute
        if (win) {
            for (int j = 0; j < n; ++j) {
                unsigned kj = keys[j];
                if ((kj >> 14) == pi && kj > ki) { win = false; break; }
            }
        }
        winflag[tid] = win ? 1 : 0;
    }
    __syncthreads();
    if (tid == 0) {
        int m = 0;
        for (int j = 0; j < n; ++j)
            if (winflag[j]) plist[m++] = (unsigned short)(keys[j] >> 14);
        // insertion sort by pos: deterministic + matches numpy sum order
        for (int a = 1; a < m; ++a) {
            unsigned short xv = plist[a]; int c = a - 1;
            while (c >= 0 && plist[c] > xv) { plist[c + 1] = plist[c]; --c; }
            plist[c + 1] = xv;
        }
        mcnt = m;
        #pragma unroll
        for (int x2 = 0; x2 < 8; ++x2) plist[m + x2] = (unsigned short)IN_;  // zero-row pad
    }
    __syncthreads();
    int m = mcnt;
    float acc = 0.f;
    for (int k = 0; k < m; k += 8) {       // 8 independent loads per round
        float w0 = w_in_T[(int)plist[k + 0] * H_ + tid];
        float w1 = w_in_T[(int)plist[k + 1] * H_ + tid];
        float w2 = w_in_T[(int)plist[k + 2] * H_ + tid];
        float w3 = w_in_T[(int)plist[k + 3] * H_ + tid];
        float w4 = w_in_T[(int)plist[k + 4] * H_ + tid];
        float w5 = w_in_T[(int)plist[k + 5] * H_ + tid];
        float w6 = w_in_T[(int)plist[k + 6] * H_ + tid];
        float w7 = w_in_T[(int)plist[k + 7] * H_ + tid];
        acc = ((((((((acc + w0) + w1) + w2) + w3) + w4) + w5) + w6) + w7);
    }
    in_cur[(size_t)t * (B_ * H_) + b * H_ + tid] = acc;
}

// ---------------------------------------------------------------------------
// Sequential LIF simulation: one block per batch.
// Waves 0-7: hidden units (thread = unit). Wave 8 (tid 512..575): readout.
// Per step: ballot -> mword -> [A] -> 8-thread compact spike list -> [B]
//           -> 16-deep batched gathers (order-preserving serial adds).
// ---------------------------------------------------------------------------
__global__ __launch_bounds__(576) void sim_k(const float* __restrict__ in_cur,
                                             const float* __restrict__ w_rec_T,
                                             const float* __restrict__ w_out_T,
                                             float* __restrict__ out) {
    int b = blockIdx.x;
    int tid = threadIdx.x;
    int wid = tid >> 6, lane = tid & 63;
    __shared__ unsigned long long mword[8];
    __shared__ unsigned short slist[2][H_ + KB];
    __shared__ int scnt[2];
    if (tid == 0) { scnt[0] = 0; scnt[1] = 0; }

    float v = 0.f, cur = 0.f;      // LIF state of unit h=tid (waves 0-7)
    float vo = 0.f, io = 0.f;      // LI readout state (wave 8, lanes 0..9)
    const float* icb = in_cur + b * H_;
    const int o = tid - H_;        // readout index for wave 8

    float inc_next = (tid < H_) ? icb[tid] : 0.f;   // prefetch t=0
    for (int t = 0; t < T_; ++t) {
        int pw = t & 1;
        float inc = inc_next;
        bool z = false;
        if (tid < H_) {
            if (t + 1 < T_)        // prefetch next step (~1 step of slack)
                inc_next = icb[(size_t)(t + 1) * (B_ * H_) + tid];
            float v_dec = fmaf(0.1f, cur - v, v);   // v + DT*TAU_MEM_INV*(i-v)
            cur *= 0.8f;                            // i * (1 - DT*TAU_SYN_INV)
            z = v_dec > 0.5f;
            v = z ? 0.f : v_dec;
        }
        unsigned long long bal = __ballot(z);
        if (lane == 0 && wid < 8) mword[wid] = bal;
        __syncthreads();                            // A: mword ready
        if (tid < 8) {
            int off = 0;
            for (int j = 0; j < tid; ++j) off += __popcll(mword[j]);
            unsigned long long m = mword[tid];
            int base = tid << 6;
            while (m) {
                int j = __builtin_ctzll(m);
                slist[pw][off++] = (unsigned short)(base + j);
                m &= m - 1;
            }
            if (tid == 7) {
                scnt[pw] = off;
                #pragma unroll
                for (int x2 = 0; x2 < KB; ++x2)
                    slist[pw][off + x2] = (unsigned short)H_;   // zero-row pad
            }
        }
        __syncthreads();                            // B: slist ready
        if (tid < H_) {
            // recurrent gather from z_prev list; 16 loads in flight per round,
            // adds serial in ascending index order (bit-exact)
            int np = scnt[pw ^ 1];
            const unsigned short* sl = slist[pw ^ 1];
            float acc = cur;
            for (int k = 0; k < np; k += KB) {
                float g0  = w_rec_T[(int)sl[k + 0]  * H_ + tid];
                float g1  = w_rec_T[(int)sl[k + 1]  * H_ + tid];
                float g2  = w_rec_T[(int)sl[k + 2]  * H_ + tid];
                float g3  = w_rec_T[(int)sl[k + 3]  * H_ + tid];
                float g4  = w_rec_T[(int)sl[k + 4]  * H_ + tid];
                float g5  = w_rec_T[(int)sl[k + 5]  * H_ + tid];
                float g6  = w_rec_T[(int)sl[k + 6]  * H_ + tid];
                float g7  = w_rec_T[(int)sl[k + 7]  * H_ + tid];
                float g8  = w_rec_T[(int)sl[k + 8]  * H_ + tid];
                float g9  = w_rec_T[(int)sl[k + 9]  * H_ + tid];
                float g10 = w_rec_T[(int)sl[k + 10] * H_ + tid];
                float g11 = w_rec_T[(int)sl[k + 11] * H_ + tid];
                float g12 = w_rec_T[(int)sl[k + 12] * H_ + tid];
                float g13 = w_rec_T[(int)sl[k + 13] * H_ + tid];
                float g14 = w_rec_T[(int)sl[k + 14] * H_ + tid];
                float g15 = w_rec_T[(int)sl[k + 15] * H_ + tid];
                acc = ((((((((((((((((acc + g0) + g1) + g2) + g3) + g4) + g5)
                        + g6) + g7) + g8) + g9) + g10) + g11) + g12) + g13)
                        + g14) + g15);
            }
            cur = acc + inc;
        } else if (o < OUT_) {
            // readout gather from z_new list (overlaps with recurrent gather)
            int nc = scnt[pw];
            const unsigned short* sl = slist[pw];
            float y = 0.f;
            for (int k = 0; k < nc; k += KB) {
                float g0  = w_out_T[(int)sl[k + 0]  * OUT_ + o];
                float g1  = w_out_T[(int)sl[k + 1]  * OUT_ + o];
                float g2  = w_out_T[(int)sl[k + 2]  * OUT_ + o];
                float g3  = w_out_T[(int)sl[k + 3]  * OUT_ + o];
                float g4  = w_out_T[(int)sl[k + 4]  * OUT_ + o];
                float g5  = w_out_T[(int)sl[k + 5]  * OUT_ + o];
                float g6  = w_out_T[(int)sl[k + 6]  * OUT_ + o];
                float g7  = w_out_T[(int)sl[k + 7]  * OUT_ + o];
                float g8  = w_out_T[(int)sl[k + 8]  * OUT_ + o];
                float g9  = w_out_T[(int)sl[k + 9]  * OUT_ + o];
                float g10 = w_out_T[(int)sl[k + 10] * OUT_ + o];
                float g11 = w_out_T[(int)sl[k + 11] * OUT_ + o];
                float g12 = w_out_T[(int)sl[k + 12] * OUT_ + o];
                float g13 = w_out_T[(int)sl[k + 13] * OUT_ + o];
                float g14 = w_out_T[(int)sl[k + 14] * OUT_ + o];
                float g15 = w_out_T[(int)sl[k + 15] * OUT_ + o];
                y = ((((((((((((((((y + g0) + g1) + g2) + g3) + g4) + g5)
                        + g6) + g7) + g8) + g9) + g10) + g11) + g12) + g13)
                        + g14) + g15);
            }
            vo = fmaf(0.1f, io - vo, vo);           // uses OLD io
            io = io * 0.8f + y;
            out[(size_t)t * (B_ * OUT_) + b * OUT_ + o] = vo;
        }
        // no extra barrier: next-step mword writes are fenced by barrier A,
        // slist[pw] next overwritten at t+2 (after A(t+2)) -> safe.
    }
}

// ---------------------------------------------------------------------------
extern "C" void kernel_launch(void* const* d_in, const int* in_sizes, int n_in,
                              void* d_out, int out_size, void* d_ws, size_t ws_size,
                              hipStream_t stream) {
    const int*   x     = (const int*)d_in[0];
    const float* w_in  = (const float*)d_in[1];
    const float* w_rec = (const float*)d_in[2];
    const float* w_out = (const float*)d_in[3];
    float* out = (float*)d_out;

    char* ws = (char*)d_ws;
    size_t off = 0;
    int*      cnt     = (int*)(ws + off);      off += (size_t)B_ * T_ * 4;                 // 32 KB
    unsigned* data    = (unsigned*)(ws + off); off += (size_t)B_ * T_ * CAP_ * 4;          // 6 MB
    float*    w_in_T  = (float*)(ws + off);    off += (size_t)(IN_ + 1) * H_ * 4;          // 8.4 MB (+zero row)
    float*    w_rec_T = (float*)(ws + off);    off += (size_t)(H_ + 1) * H_ * 4;           // 1.05 MB (+zero row)
    float*    w_out_T = (float*)(ws + off);    off += (size_t)(H_ + 1) * OUT_ * 4;         // 20.5 KB (+zero row)
    float*    in_cur  = (float*)(ws + off);    off += (size_t)T_ * B_ * H_ * 4;            // 16 MB

    hipMemsetAsync(cnt, 0, (size_t)B_ * T_ * 4, stream);
    hipMemsetAsync(w_in_T + (size_t)IN_ * H_, 0, H_ * 4, stream);       // zero pad row
    hipMemsetAsync(w_rec_T + (size_t)H_ * H_, 0, H_ * 4, stream);       // zero pad row
    hipMemsetAsync(w_out_T + (size_t)H_ * OUT_, 0, OUT_ * 4, stream);   // zero pad row

    dim3 tb(32, 8);
    transpose_k<<<dim3(IN_ / 32, H_ / 32), tb, 0, stream>>>(w_in, w_in_T, H_, IN_);
    transpose_k<<<dim3(H_ / 32, H_ / 32), tb, 0, stream>>>(w_rec, w_rec_T, H_, H_);
    transpose_k<<<dim3(H_ / 32, 1), tb, 0, stream>>>(w_out, w_out_T, OUT_, H_);

    scatter_k<<<(B_ * S_) / 256, 256, 0, stream>>>((const int4*)x, cnt, data);

    incur_k<<<B_ * T_, 512, 0, stream>>>(cnt, data, w_in_T, in_cur);

    sim_k<<<B_, 576, 0, stream>>>(in_cur, w_rec_T, w_out_T, out);
}

// Round 4
// 126.573 us; speedup vs baseline: 3.9344x; 2.9580x over previous
//
#include <hip/hip_runtime.h>

#define B_   32
#define S_   8192
#define T_   256
#define IN_  4096
#define H_   512
#define OUT_ 10
#define CAP_ 192   // max events per (b,t) bucket; max observed ~70 (Poisson(32))
#define CH   16    // sim steps per speculative chunk
#define NCH  (T_ / CH)

// ---------------------------------------------------------------------------
// Fused prep: z=0 transpose w_in, z=1 transpose w_rec, z=2 event scatter.
// block = (32,8)
// ---------------------------------------------------------------------------
__global__ void prep_k(const float* __restrict__ w_in, const float* __restrict__ w_rec,
                       const int4* __restrict__ x,
                       float* __restrict__ w_in_T, float* __restrict__ w_rec_T,
                       int* __restrict__ cnt, unsigned* __restrict__ data) {
    int zz = blockIdx.z;
    int tx = threadIdx.x, ty = threadIdx.y;
    if (zz == 2) {
        // ---- scatter: key = (pos<<14)|(s<<1)|val; max key per pos = last event
        int flat = blockIdx.y * gridDim.x + blockIdx.x;
        if (flat >= (B_ * S_) / 256) return;
        int e = flat * 256 + ty * 32 + tx;
        int4 ev = x[e];                       // cx, cy, val, ts
        int b = e >> 13;                      // S_ = 8192
        int s = e & (S_ - 1);
        unsigned pos = (unsigned)(ev.x * ev.y);
        unsigned key = (pos << 14) | ((unsigned)s << 1) | (unsigned)ev.z;
        int bucket = b * T_ + ev.w;
        int slot = atomicAdd(&cnt[bucket], 1);
        if (slot < CAP_) data[bucket * CAP_ + slot] = key;
        return;
    }
    // ---- transpose src[R][C] -> dst[C][R]
    const float* src = zz ? w_rec : w_in;
    float* dst = zz ? w_rec_T : w_in_T;
    const int R = H_, C = zz ? H_ : IN_;
    int bx = blockIdx.x * 32, by = blockIdx.y * 32;
    if (bx >= C || by >= R) return;
    __shared__ float tile[32][33];
    #pragma unroll
    for (int k = 0; k < 32; k += 8) {
        int r = by + ty + k, c = bx + tx;
        if (r < R && c < C) tile[ty + k][tx] = src[(size_t)r * C + c];
    }
    __syncthreads();
    #pragma unroll
    for (int k = 0; k < 32; k += 8) {
        int c = bx + ty + k, r = by + tx;
        if (c < C && r < R) dst[(size_t)c * R + r] = tile[tx][ty + k];
    }
}

// ---------------------------------------------------------------------------
// Per-bucket dedup + input-current accumulation (block per (b,t), 512 thr).
// Parallel winner-flag + parallel rank (no serial sort): plist sorted by pos.
// ---------------------------------------------------------------------------
__global__ __launch_bounds__(512) void incur_k(const int* __restrict__ cnt,
                                               const unsigned* __restrict__ data,
                                               const float* __restrict__ w_in_T,
                                               float* __restrict__ in_cur) {
    int bucket = blockIdx.x;       // b*T_ + t
    int b = bucket >> 8;
    int t = bucket & (T_ - 1);
    __shared__ unsigned keys[CAP_];
    __shared__ unsigned char wf[CAP_];
    __shared__ unsigned short plist[CAP_];
    int tid = threadIdx.x;
    int n = cnt[bucket]; if (n > CAP_) n = CAP_;
    if (tid < n) keys[tid] = data[bucket * CAP_ + tid];
    __syncthreads();
    bool win = false;
    unsigned ki = 0;
    if (tid < n) {
        ki = keys[tid];
        unsigned pi = ki >> 14;
        win = (ki & 1u) != 0u;                // only val==1 winners contribute
        if (win) {
            for (int j = 0; j < n; ++j) {
                unsigned kj = keys[j];
                if ((kj >> 14) == pi && kj > ki) { win = false; break; }
            }
        }
        wf[tid] = win ? 1 : 0;
    }
    int m = __syncthreads_count(win);         // barrier: wf/keys visible
    if (win) {
        int r = 0;                            // rank among winners by pos
        for (int j = 0; j < n; ++j)
            r += (wf[j] && keys[j] < ki);     // winners have distinct pos
        plist[r] = (unsigned short)(ki >> 14);
    }
    __syncthreads();                          // plist ready
    float acc = 0.f;
    for (int k = 0; k < m; k += 8) {          // 8 loads in flight per round
        int i0 = k + 0 < m ? k + 0 : m - 1;  float g0 = w_in_T[(int)plist[i0] * H_ + tid];
        int i1 = k + 1 < m ? k + 1 : m - 1;  float g1 = w_in_T[(int)plist[i1] * H_ + tid];
        int i2 = k + 2 < m ? k + 2 : m - 1;  float g2 = w_in_T[(int)plist[i2] * H_ + tid];
        int i3 = k + 3 < m ? k + 3 : m - 1;  float g3 = w_in_T[(int)plist[i3] * H_ + tid];
        int i4 = k + 4 < m ? k + 4 : m - 1;  float g4 = w_in_T[(int)plist[i4] * H_ + tid];
        int i5 = k + 5 < m ? k + 5 : m - 1;  float g5 = w_in_T[(int)plist[i5] * H_ + tid];
        int i6 = k + 6 < m ? k + 6 : m - 1;  float g6 = w_in_T[(int)plist[i6] * H_ + tid];
        int i7 = k + 7 < m ? k + 7 : m - 1;  float g7 = w_in_T[(int)plist[i7] * H_ + tid];
        acc = acc + (k + 0 < m ? g0 : 0.f);
        acc = acc + (k + 1 < m ? g1 : 0.f);
        acc = acc + (k + 2 < m ? g2 : 0.f);
        acc = acc + (k + 3 < m ? g3 : 0.f);
        acc = acc + (k + 4 < m ? g4 : 0.f);
        acc = acc + (k + 5 < m ? g5 : 0.f);
        acc = acc + (k + 6 < m ? g6 : 0.f);
        acc = acc + (k + 7 < m ? g7 : 0.f);
    }
    in_cur[(size_t)t * (B_ * H_) + b * H_ + tid] = acc;
}

// ---------------------------------------------------------------------------
// Speculative chunked LIF simulation. One block per batch, thread = unit.
// Fast path: 16 steps of pure VALU, one __syncthreads_or per chunk.
// Cold path (spike detected): rollback + exact per-step replay with the full
// ballot/LDS machinery in numpy's summation order.
// ---------------------------------------------------------------------------
__global__ __launch_bounds__(512) void sim_k(const float* __restrict__ in_cur,
                                             const float* __restrict__ w_rec_T,
                                             const float* __restrict__ w_out,
                                             float* __restrict__ out) {
    int b = blockIdx.x;
    int tid = threadIdx.x;
    int wid = tid >> 6, lane = tid & 63;
    __shared__ unsigned long long mword[8];

    const float* icb = in_cur + b * H_ + tid;        // &in_cur[t=0][b][tid]
    float* outp = out + b * OUT_ + tid;              // valid when tid < OUT_

    float v = 0.f, cur = 0.f;     // LIF state of unit h = tid
    float vo = 0.f, io = 0.f;     // LI readout state (tid < 10)

    float ib0[CH], ib1[CH];
    #pragma unroll
    for (int s = 0; s < CH; ++s) ib0[s] = icb[(size_t)s * (B_ * H_)];
    #pragma unroll
    for (int s = 0; s < CH; ++s) ib1[s] = icb[(size_t)(CH + s) * (B_ * H_)];

    auto run_chunk = [&](float (&ib)[CH], int c) {
        float v0 = v, cur0 = cur, vo0 = vo, io0 = io;   // rollback snapshot
        float vmax = -1e30f;
        // ---- fast path: assume no spikes in this chunk
        #pragma unroll
        for (int s = 0; s < CH; ++s) {
            float vd = v + 0.1f * (cur - v);
            vmax = fmaxf(vmax, vd);
            v = vd;
            cur = cur * 0.8f + ib[s];
            if (tid < OUT_) {
                float von = vo + 0.1f * (io - vo);   // uses OLD io
                io = io * 0.8f;                      // y == 0
                outp[(size_t)(c * CH + s) * (B_ * OUT_)] = von;
                vo = von;
            }
        }
        int any = __syncthreads_or(vmax > 0.45f);    // margin below V_TH=0.5
        if (any) {
            // ---- cold path: exact replay with spikes (numpy order)
            v = v0; cur = cur0; vo = vo0; io = io0;
            #pragma unroll 1
            for (int s = 0; s < CH; ++s) {
                float vd = v + 0.1f * (cur - v);
                bool z = vd > 0.5f;
                v = z ? 0.0f : vd;
                unsigned long long bal = __ballot(z);
                if (lane == 0) mword[wid] = bal;
                __syncthreads();
                float c2 = cur * 0.8f + ib[s];       // i_dec + input first
                for (int w = 0; w < 8; ++w) {        // then rec, ascending j
                    unsigned long long m = mword[w];
                    while (m) {
                        int j = __builtin_ctzll(m);
                        c2 += w_rec_T[(size_t)((w << 6) + j) * H_ + tid];
                        m &= m - 1;
                    }
                }
                cur = c2;
                if (tid < OUT_) {
                    float y = 0.f;
                    for (int w = 0; w < 8; ++w) {
                        unsigned long long m = mword[w];
                        while (m) {
                            int j = __builtin_ctzll(m);
                            y += w_out[tid * H_ + (w << 6) + j];
                            m &= m - 1;
                        }
                    }
                    float von = vo + 0.1f * (io - vo);
                    io = io * 0.8f + y;
                    outp[(size_t)(c * CH + s) * (B_ * OUT_)] = von;  // overwrite
                    vo = von;
                }
                __syncthreads();                     // protect mword reuse
            }
        }
        // ---- prefetch chunk c+2 into the buffer just consumed
        if (c + 2 < NCH) {
            #pragma unroll
            for (int s = 0; s < CH; ++s)
                ib[s] = icb[(size_t)((c + 2) * CH + s) * (B_ * H_)];
        }
    };

    for (int c = 0; c < NCH; c += 2) {
        run_chunk(ib0, c);
        run_chunk(ib1, c + 1);
    }
}

// ---------------------------------------------------------------------------
extern "C" void kernel_launch(void* const* d_in, const int* in_sizes, int n_in,
                              void* d_out, int out_size, void* d_ws, size_t ws_size,
                              hipStream_t stream) {
    const int*   x     = (const int*)d_in[0];
    const float* w_in  = (const float*)d_in[1];
    const float* w_rec = (const float*)d_in[2];
    const float* w_out = (const float*)d_in[3];
    float* out = (float*)d_out;

    char* ws = (char*)d_ws;
    size_t off = 0;
    int*      cnt     = (int*)(ws + off);      off += (size_t)B_ * T_ * 4;            // 32 KB
    unsigned* data    = (unsigned*)(ws + off); off += (size_t)B_ * T_ * CAP_ * 4;     // 6 MB
    float*    w_in_T  = (float*)(ws + off);    off += (size_t)IN_ * H_ * 4;           // 8 MB
    float*    w_rec_T = (float*)(ws + off);    off += (size_t)H_ * H_ * 4;            // 1 MB
    float*    in_cur  = (float*)(ws + off);    off += (size_t)T_ * B_ * H_ * 4;       // 16 MB

    (void)hipMemsetAsync(cnt, 0, (size_t)B_ * T_ * 4, stream);

    // z=0: w_in transpose (128x16 tiles); z=1: w_rec (16x16); z=2: scatter (1024 blocks)
    prep_k<<<dim3(128, 16, 3), dim3(32, 8), 0, stream>>>(w_in, w_rec, (const int4*)x,
                                                         w_in_T, w_rec_T, cnt, data);

    incur_k<<<B_ * T_, 512, 0, stream>>>(cnt, data, w_in_T, in_cur);

    sim_k<<<B_, 512, 0, stream>>>(in_cur, w_rec_T, w_out, out);
}